// Round 3
// baseline (1574.337 us; speedup 1.0000x reference)
//
#include <hip/hip_runtime.h>
#include <hip/hip_bf16.h>

#define BB 16
#define NXX 1024
#define NYY 1024
#define DINX 768
#define DINY 283
#define NHH 8
#define HKK 10
#define DKV 80
#define NORMF 0.31622776601683794f  // 1/sqrt(10)

#define QT 32    // q rows per attention block
#define KC 128   // k chunk staged in LDS
#define SLD 1040 // S row stride in bf16 elems

// ---------------- fused projections ----------------
// 512 blocks x 512 threads. Blocks 0..255: Q = X @ Wq^T (Din=768).
// Blocks 256..511: K,V = Y @ {Wk,Wv}^T (Din=283, shared Y tile).
// Thread tile: 2 rows x 5 cols (Q) / 2 rows x (5+5) cols (KV). 64-row block tiles.
__global__ __launch_bounds__(512, 4) void proj_kernel(
    const float* __restrict__ X, const float* __restrict__ Y,
    const float* __restrict__ Wq, const float* __restrict__ Wk, const float* __restrict__ Wv,
    float* __restrict__ Qw, float* __restrict__ Kw, float* __restrict__ Vw) {
  __shared__ float Xs[64 * 68];
  __shared__ float Ws[160 * 68];
  const int t = threadIdx.x;
  const bool isQ = (blockIdx.x < 256);
  const int rb = (isQ ? blockIdx.x : blockIdx.x - 256) * 64;
  const int tc = t & 15;   // cols tc + 16j
  const int tr = t >> 4;   // rows tr*2 + i

  if (isQ) {
    float acc[2][5];
#pragma unroll
    for (int i = 0; i < 2; ++i)
#pragma unroll
      for (int j = 0; j < 5; ++j) acc[i][j] = 0.f;

    for (int ch = 0; ch < 12; ++ch) {  // 768 = 12*64
      const int dk = ch << 6;
      __syncthreads();
      for (int u = t; u < 1024; u += 512) {      // X tile 64x64, float4 (768-stride: aligned)
        int r = u >> 4, c4 = u & 15;
        *(float4*)&Xs[r * 68 + c4 * 4] = *(const float4*)&X[(size_t)(rb + r) * DINX + dk + c4 * 4];
      }
      for (int u = t; u < 1280; u += 512) {      // Wq tile 80x64
        int r = u >> 4, c4 = u & 15;
        *(float4*)&Ws[r * 68 + c4 * 4] = *(const float4*)&Wq[(size_t)r * DINX + dk + c4 * 4];
      }
      __syncthreads();
#pragma unroll
      for (int dv = 0; dv < 16; ++dv) {
        float4 xv0 = *(const float4*)&Xs[(tr * 2 + 0) * 68 + dv * 4];
        float4 xv1 = *(const float4*)&Xs[(tr * 2 + 1) * 68 + dv * 4];
        float4 wv[5];
#pragma unroll
        for (int j = 0; j < 5; ++j)
          wv[j] = *(const float4*)&Ws[(tc + 16 * j) * 68 + dv * 4];
#pragma unroll
        for (int j = 0; j < 5; ++j) {
          acc[0][j] += xv0.x * wv[j].x + xv0.y * wv[j].y + xv0.z * wv[j].z + xv0.w * wv[j].w;
          acc[1][j] += xv1.x * wv[j].x + xv1.y * wv[j].y + xv1.z * wv[j].z + xv1.w * wv[j].w;
        }
      }
    }
#pragma unroll
    for (int i = 0; i < 2; ++i)
#pragma unroll
      for (int j = 0; j < 5; ++j)
        Qw[(size_t)(rb + tr * 2 + i) * DKV + tc + 16 * j] = acc[i][j];
  } else {
    float acc[2][10];
#pragma unroll
    for (int i = 0; i < 2; ++i)
#pragma unroll
      for (int j = 0; j < 10; ++j) acc[i][j] = 0.f;

    for (int ch = 0; ch < 5; ++ch) {   // 283 = 4*64 + 27
      const int dk = ch << 6;
      __syncthreads();
      // scalar staging (stride 283 is not 16B-aligned), zero-fill past Din
      for (int u = t; u < 4096; u += 512) {
        int r = u >> 6, c = u & 63;
        int d = dk + c;
        Xs[r * 68 + c] = (d < DINY) ? Y[(size_t)(rb + r) * DINY + d] : 0.f;
      }
      for (int u = t; u < 10240; u += 512) {
        int r = u >> 6, c = u & 63;
        int d = dk + c;
        float v = 0.f;
        if (d < DINY) v = (r < 80) ? Wk[(size_t)r * DINY + d] : Wv[(size_t)(r - 80) * DINY + d];
        Ws[r * 68 + c] = v;
      }
      __syncthreads();
#pragma unroll
      for (int dv = 0; dv < 16; ++dv) {
        float4 xv0 = *(const float4*)&Xs[(tr * 2 + 0) * 68 + dv * 4];
        float4 xv1 = *(const float4*)&Xs[(tr * 2 + 1) * 68 + dv * 4];
        float4 wv[10];
#pragma unroll
        for (int j = 0; j < 5; ++j) {
          wv[j] = *(const float4*)&Ws[(tc + 16 * j) * 68 + dv * 4];
          wv[5 + j] = *(const float4*)&Ws[(80 + tc + 16 * j) * 68 + dv * 4];
        }
#pragma unroll
        for (int j = 0; j < 10; ++j) {
          acc[0][j] += xv0.x * wv[j].x + xv0.y * wv[j].y + xv0.z * wv[j].z + xv0.w * wv[j].w;
          acc[1][j] += xv1.x * wv[j].x + xv1.y * wv[j].y + xv1.z * wv[j].z + xv1.w * wv[j].w;
        }
      }
    }
#pragma unroll
    for (int i = 0; i < 2; ++i)
#pragma unroll
      for (int j = 0; j < 5; ++j) {
        Kw[(size_t)(rb + tr * 2 + i) * DKV + tc + 16 * j] = acc[i][j];
        Vw[(size_t)(rb + tr * 2 + i) * DKV + tc + 16 * j] = acc[i][5 + j];
      }
  }
}

// ---------------- fused attention ----------------
// grid: B*NH*32 blocks; block = (b,h, 32 q rows); 512 threads = 8 waves.
// Wave w owns q rows 4w..4w+3 (Q_PER=4 amortizes K/V LDS reads); 64 lanes = k-split
// entirely in-wave -> shfl_xor butterfly reduction, no cross-wave exchange.
// Phase A: dot+exp once, p -> bf16 S in LDS, l & PV in registers.
// Phase B: scale + coalesced float4 dist stores.
__global__ __launch_bounds__(512, 4) void attn_kernel(
    const float* __restrict__ Qw, const float* __restrict__ Kw,
    const float* __restrict__ Vw, float* __restrict__ out_att,
    float* __restrict__ out_dist) {
  __shared__ __hip_bfloat16 S[QT * SLD];  // 66560 B
  __shared__ float Ks[KC * 12];           // 6144 B
  __shared__ float Vs[KC * 12];           // 6144 B
  __shared__ float rls[QT];

  const int t = threadIdx.x;
  const int bid = blockIdx.x;
  const int qt = bid & 31;          // q-tile fast -> same (b,h) adjacent for K/V L2 reuse
  const int h = (bid >> 5) & 7;
  const int b = bid >> 8;

  const int w = t >> 6;             // wave id -> q group
  const int kl = t & 63;

  float qr[4][10];
#pragma unroll
  for (int qi = 0; qi < 4; ++qi) {
    const float2* qp = (const float2*)(Qw + ((size_t)b * NXX + qt * QT + w * 4 + qi) * DKV + h * HKK);
#pragma unroll
    for (int dd = 0; dd < 5; ++dd) {
      float2 v = qp[dd];
      qr[qi][2 * dd] = v.x * NORMF;
      qr[qi][2 * dd + 1] = v.y * NORMF;
    }
  }

  float acc[4][10];
#pragma unroll
  for (int qi = 0; qi < 4; ++qi)
#pragma unroll
    for (int d = 0; d < 10; ++d) acc[qi][d] = 0.f;
  float lsum[4] = {0.f, 0.f, 0.f, 0.f};

  for (int ch = 0; ch < NYY / KC; ++ch) {
    __syncthreads();
    for (int u = t; u < 1280; u += 512) {  // stage K,V chunk as float2 units
      int m = (u >= 640);
      int i = m ? u - 640 : u;
      int row = i / 5, j = i - row * 5;
      const float* src = (m ? Vw : Kw) + ((size_t)b * NYY + ch * KC + row) * DKV + h * HKK + j * 2;
      float2 v = *(const float2*)src;
      *(float2*)((m ? Vs : Ks) + row * 12 + j * 2) = v;
    }
    __syncthreads();
#pragma unroll
    for (int kk = 0; kk < 2; ++kk) {
      const int k = (kk << 6) + kl;
      const float* kp = &Ks[k * 12];
      float4 k0 = *(const float4*)kp;
      float4 k1 = *(const float4*)(kp + 4);
      float2 k2 = *(const float2*)(kp + 8);
      float p[4];
#pragma unroll
      for (int qi = 0; qi < 4; ++qi) {
        float s = qr[qi][0] * k0.x + qr[qi][1] * k0.y + qr[qi][2] * k0.z + qr[qi][3] * k0.w +
                  qr[qi][4] * k1.x + qr[qi][5] * k1.y + qr[qi][6] * k1.z + qr[qi][7] * k1.w +
                  qr[qi][8] * k2.x + qr[qi][9] * k2.y;
        p[qi] = __expf(s);
        lsum[qi] += p[qi];
        S[(w * 4 + qi) * SLD + (ch << 7) + k] = __float2bfloat16(p[qi]);
      }
      const float* vp = &Vs[k * 12];
      float4 v0 = *(const float4*)vp;
      float4 v1 = *(const float4*)(vp + 4);
      float2 v2 = *(const float2*)(vp + 8);
#pragma unroll
      for (int qi = 0; qi < 4; ++qi) {
        acc[qi][0] += p[qi] * v0.x; acc[qi][1] += p[qi] * v0.y;
        acc[qi][2] += p[qi] * v0.z; acc[qi][3] += p[qi] * v0.w;
        acc[qi][4] += p[qi] * v1.x; acc[qi][5] += p[qi] * v1.y;
        acc[qi][6] += p[qi] * v1.z; acc[qi][7] += p[qi] * v1.w;
        acc[qi][8] += p[qi] * v2.x; acc[qi][9] += p[qi] * v2.y;
      }
    }
  }

  // in-wave butterfly allreduce over the 64-lane k-split
#pragma unroll
  for (int off = 32; off; off >>= 1) {
#pragma unroll
    for (int qi = 0; qi < 4; ++qi) {
      lsum[qi] += __shfl_xor(lsum[qi], off);
#pragma unroll
      for (int d = 0; d < 10; ++d) acc[qi][d] += __shfl_xor(acc[qi][d], off);
    }
  }

  if (kl == 0) {
#pragma unroll
    for (int qi = 0; qi < 4; ++qi) {
      const int q = w * 4 + qi;
      const float rl = 1.0f / lsum[qi];
      rls[q] = rl;
      float* ap = out_att + ((size_t)b * NXX + qt * QT + q) * DKV + h * HKK;
#pragma unroll
      for (int dd = 0; dd < 5; ++dd)
        *(float2*)&ap[2 * dd] = make_float2(acc[qi][2 * dd] * rl, acc[qi][2 * dd + 1] * rl);
    }
  }
  __syncthreads();

  // phase B: 32x1024 elems, float4 stores, fully coalesced
  const size_t dbase = (((size_t)(b * NHH + h)) * NXX + qt * QT) * NYY;
#pragma unroll 2
  for (int it = 0; it < 16; ++it) {
    const int e = it * 2048 + (t << 2);
    const int qq = e >> 10;
    const int kk = e & 1023;
    uint2 wv = *(const uint2*)&S[qq * SLD + kk];
    const float rlq = rls[qq];
    float4 o;
    o.x = __uint_as_float(wv.x << 16) * rlq;
    o.y = __uint_as_float(wv.x & 0xffff0000u) * rlq;
    o.z = __uint_as_float(wv.y << 16) * rlq;
    o.w = __uint_as_float(wv.y & 0xffff0000u) * rlq;
    *(float4*)(out_dist + dbase + (size_t)qq * NYY + kk) = o;
  }
}

extern "C" void kernel_launch(void* const* d_in, const int* in_sizes, int n_in,
                              void* d_out, int out_size, void* d_ws, size_t ws_size,
                              hipStream_t stream) {
  (void)in_sizes; (void)n_in; (void)out_size; (void)ws_size;
  const float* x = (const float*)d_in[0];
  const float* y = (const float*)d_in[1];
  // d_in[2] = attn_mask (dead arg in the reference forward)
  const float* Wq = (const float*)d_in[3];
  const float* Wk = (const float*)d_in[4];
  const float* Wv = (const float*)d_in[5];

  float* out = (float*)d_out;
  float* att_out = out;
  float* dist_out = out + (size_t)BB * NXX * DKV;

  float* Qw = (float*)d_ws;                 // [16384, 80]
  float* Kw = Qw + (size_t)BB * NXX * DKV;  // [16384, 80]
  float* Vw = Kw + (size_t)BB * NYY * DKV;  // [16384, 80]

  proj_kernel<<<512, 512, 0, stream>>>(x, y, Wq, Wk, Wv, Qw, Kw, Vw);
  attn_kernel<<<BB * NHH * 32, 512, 0, stream>>>(Qw, Kw, Vw, att_out, dist_out);
}

// Round 4
// 1047.906 us; speedup vs baseline: 1.5024x; 1.5024x over previous
//
#include <hip/hip_runtime.h>
#include <hip/hip_bf16.h>

#define BB 16
#define NXX 1024
#define NYY 1024
#define DINX 768
#define DINY 283
#define NHH 8
#define HKK 10
#define DKV 80
#define NORMF 0.31622776601683794f  // 1/sqrt(10)

#define QT 32    // q rows per attention block
#define KC 128   // k chunk staged in LDS
#define SLD 1040 // S row stride in bf16 elems

// ---------------- projections: lane = row, 40 cols per work item ----------------
// W addresses are wave-uniform -> scalar loads (s_load) through the K-cache;
// inner loop is v_fmac(acc_vgpr, w_sgpr, x_vgpr). No LDS, no barriers, no spill.
template <int DIN, int NCHUNK, int TAIL>
__device__ __forceinline__ void proj_body(
    const float* __restrict__ src, const float* __restrict__ W,
    float* __restrict__ dst, int r64, int cg40) {
  const int lane = threadIdx.x;  // 0..63
  const int row = r64 * 64 + lane;
  const float* xrow = src + (size_t)row * DIN;
  const float* wbase = W + (size_t)cg40 * DIN;

  float acc[40];
#pragma unroll
  for (int c = 0; c < 40; ++c) acc[c] = 0.f;

#pragma unroll 1
  for (int ch = 0; ch < NCHUNK; ++ch) {
    const int dk = ch * 16;
    float xv[16];
    if constexpr ((DIN & 15) == 0) {
      const float4* xp = (const float4*)(xrow + dk);
#pragma unroll
      for (int i = 0; i < 4; ++i) {
        float4 v = xp[i];
        xv[4 * i] = v.x; xv[4 * i + 1] = v.y; xv[4 * i + 2] = v.z; xv[4 * i + 3] = v.w;
      }
    } else {
#pragma unroll
      for (int k = 0; k < 16; ++k) xv[k] = xrow[dk + k];
    }
#pragma unroll
    for (int c = 0; c < 40; ++c) {
      const float* wr = wbase + (size_t)c * DIN + dk;  // uniform -> s_load
#pragma unroll
      for (int k = 0; k < 16; ++k) acc[c] = fmaf(wr[k], xv[k], acc[c]);
    }
  }
  if constexpr (TAIL > 0) {
    const int dk = NCHUNK * 16;
    float xv[TAIL > 0 ? TAIL : 1];
#pragma unroll
    for (int k = 0; k < TAIL; ++k) xv[k] = xrow[dk + k];
#pragma unroll
    for (int c = 0; c < 40; ++c) {
      const float* wr = wbase + (size_t)c * DIN + dk;
#pragma unroll
      for (int k = 0; k < TAIL; ++k) acc[c] = fmaf(wr[k], xv[k], acc[c]);
    }
  }
  float* drow = dst + (size_t)row * DKV + cg40;
#pragma unroll
  for (int c = 0; c < 40; ++c) drow[c] = acc[c];
}

// grid 1536 x 64 threads. items 0..511: Q (r64 = item>>1, cols 40*(item&1)).
// items 512..1535: KV (idx>>2 = r64; idx&3: 0,1 -> K cols 0/40; 2,3 -> V cols 0/40).
__global__ __launch_bounds__(64) void proj_rows(
    const float* __restrict__ X, const float* __restrict__ Y,
    const float* __restrict__ Wq, const float* __restrict__ Wk, const float* __restrict__ Wv,
    float* __restrict__ Qw, float* __restrict__ Kw, float* __restrict__ Vw) {
  const int item = blockIdx.x;
  if (item < 512) {
    proj_body<DINX, 48, 0>(X, Wq, Qw, item >> 1, (item & 1) * 40);
  } else {
    const int i2 = item - 512;
    const int r64 = i2 >> 2;
    const int cg = i2 & 3;
    if (cg < 2) proj_body<DINY, 17, 11>(Y, Wk, Kw, r64, cg * 40);
    else        proj_body<DINY, 17, 11>(Y, Wv, Vw, r64, (cg - 2) * 40);
  }
}

// ---------------- fused attention ----------------
// block = (b,h, 32 q rows); 512 threads = 8 waves; wave owns 4 q rows x 64-lane k-split.
// K/V staged in LDS as SoA float2 [5][KC] -> wave reads are consecutive b64, conflict-free.
// Phase A: dot+exp once, p -> bf16 S tile, l & PV in registers, in-wave butterfly reduce.
// Phase B: scale by 1/l, coalesced float4 dist stores.
__global__ __launch_bounds__(512, 2) void attn_kernel(
    const float* __restrict__ Qw, const float* __restrict__ Kw,
    const float* __restrict__ Vw, float* __restrict__ out_att,
    float* __restrict__ out_dist) {
  __shared__ __hip_bfloat16 S[QT * SLD];  // 66560 B
  __shared__ float2 Ks2[5 * KC];          // 5120 B
  __shared__ float2 Vs2[5 * KC];          // 5120 B
  __shared__ float rls[QT];

  const int t = threadIdx.x;
  const int bid = blockIdx.x;
  const int qt = bid & 31;          // q-tile fast -> same (b,h) adjacent for K/V L2 reuse
  const int h = (bid >> 5) & 7;
  const int b = bid >> 8;

  const int w = t >> 6;             // wave id -> q group (4 rows)
  const int kl = t & 63;

  float qr[4][10];
#pragma unroll
  for (int qi = 0; qi < 4; ++qi) {
    const float2* qp = (const float2*)(Qw + ((size_t)b * NXX + qt * QT + w * 4 + qi) * DKV + h * HKK);
#pragma unroll
    for (int dd = 0; dd < 5; ++dd) {
      float2 v = qp[dd];
      qr[qi][2 * dd] = v.x * NORMF;
      qr[qi][2 * dd + 1] = v.y * NORMF;
    }
  }

  float acc[4][10];
#pragma unroll
  for (int qi = 0; qi < 4; ++qi)
#pragma unroll
    for (int d = 0; d < 10; ++d) acc[qi][d] = 0.f;
  float lsum[4] = {0.f, 0.f, 0.f, 0.f};

#pragma unroll 1
  for (int ch = 0; ch < NYY / KC; ++ch) {
    __syncthreads();
    // stage K,V chunk as SoA float2: Ks2[j*KC + k] = Kw[row k, dims 2j..2j+1]
    for (int u = t; u < 10 * KC; u += 512) {
      const int m = (u >= 5 * KC);
      const int i = m ? u - 5 * KC : u;
      const int j = i >> 7;          // 0..4
      const int k = i & (KC - 1);
      const float* srcp = (m ? Vw : Kw) +
          ((size_t)b * NYY + ch * KC + k) * DKV + h * HKK + j * 2;
      float2 v = *(const float2*)srcp;
      (m ? Vs2 : Ks2)[j * KC + k] = v;
    }
    __syncthreads();
#pragma unroll
    for (int kk = 0; kk < KC / 64; ++kk) {
      const int k = (kk << 6) + kl;
      float kf[10];
#pragma unroll
      for (int j = 0; j < 5; ++j) {
        float2 v = Ks2[j * KC + k];
        kf[2 * j] = v.x; kf[2 * j + 1] = v.y;
      }
      float p[4];
#pragma unroll
      for (int qi = 0; qi < 4; ++qi) {
        float s = qr[qi][0] * kf[0] + qr[qi][1] * kf[1] + qr[qi][2] * kf[2] +
                  qr[qi][3] * kf[3] + qr[qi][4] * kf[4] + qr[qi][5] * kf[5] +
                  qr[qi][6] * kf[6] + qr[qi][7] * kf[7] + qr[qi][8] * kf[8] +
                  qr[qi][9] * kf[9];
        p[qi] = __expf(s);
        lsum[qi] += p[qi];
        S[(w * 4 + qi) * SLD + (ch << 7) + k] = __float2bfloat16(p[qi]);
      }
      float vf[10];
#pragma unroll
      for (int j = 0; j < 5; ++j) {
        float2 v = Vs2[j * KC + k];
        vf[2 * j] = v.x; vf[2 * j + 1] = v.y;
      }
#pragma unroll
      for (int qi = 0; qi < 4; ++qi)
#pragma unroll
        for (int d = 0; d < 10; ++d) acc[qi][d] += p[qi] * vf[d];
    }
  }

  // in-wave butterfly allreduce over the 64-lane k-split
#pragma unroll
  for (int off = 32; off; off >>= 1) {
#pragma unroll
    for (int qi = 0; qi < 4; ++qi) {
      lsum[qi] += __shfl_xor(lsum[qi], off);
#pragma unroll
      for (int d = 0; d < 10; ++d) acc[qi][d] += __shfl_xor(acc[qi][d], off);
    }
  }

  if (kl == 0) {
#pragma unroll
    for (int qi = 0; qi < 4; ++qi) {
      const int q = w * 4 + qi;
      const float rl = 1.0f / lsum[qi];
      rls[q] = rl;
      float* ap = out_att + ((size_t)b * NXX + qt * QT + q) * DKV + h * HKK;
#pragma unroll
      for (int dd = 0; dd < 5; ++dd)
        *(float2*)&ap[2 * dd] = make_float2(acc[qi][2 * dd] * rl, acc[qi][2 * dd + 1] * rl);
    }
  }
  __syncthreads();

  // phase B: 32x1024 elems, float4 stores, fully coalesced
  const size_t dbase = (((size_t)(b * NHH + h)) * NXX + qt * QT) * NYY;
#pragma unroll 2
  for (int it = 0; it < 16; ++it) {
    const int e = it * 2048 + (t << 2);
    const int qq = e >> 10;
    const int kk = e & 1023;
    uint2 wv = *(const uint2*)&S[qq * SLD + kk];
    const float rlq = rls[qq];
    float4 o;
    o.x = __uint_as_float(wv.x << 16) * rlq;
    o.y = __uint_as_float(wv.x & 0xffff0000u) * rlq;
    o.z = __uint_as_float(wv.y << 16) * rlq;
    o.w = __uint_as_float(wv.y & 0xffff0000u) * rlq;
    *(float4*)(out_dist + dbase + (size_t)qq * NYY + kk) = o;
  }
}

extern "C" void kernel_launch(void* const* d_in, const int* in_sizes, int n_in,
                              void* d_out, int out_size, void* d_ws, size_t ws_size,
                              hipStream_t stream) {
  (void)in_sizes; (void)n_in; (void)out_size; (void)ws_size;
  const float* x = (const float*)d_in[0];
  const float* y = (const float*)d_in[1];
  // d_in[2] = attn_mask (dead arg in the reference forward)
  const float* Wq = (const float*)d_in[3];
  const float* Wk = (const float*)d_in[4];
  const float* Wv = (const float*)d_in[5];

  float* out = (float*)d_out;
  float* att_out = out;
  float* dist_out = out + (size_t)BB * NXX * DKV;

  float* Qw = (float*)d_ws;                 // [16384, 80]
  float* Kw = Qw + (size_t)BB * NXX * DKV;  // [16384, 80]
  float* Vw = Kw + (size_t)BB * NYY * DKV;  // [16384, 80]

  proj_rows<<<1536, 64, 0, stream>>>(x, y, Wq, Wk, Wv, Qw, Kw, Vw);
  attn_kernel<<<BB * NHH * QT, 512, 0, stream>>>(Qw, Kw, Vw, att_out, dist_out);
}

// Round 5
// 563.832 us; speedup vs baseline: 2.7922x; 1.8585x over previous
//
#include <hip/hip_runtime.h>
#include <hip/hip_bf16.h>

#define BB 16
#define NXX 1024
#define NYY 1024
#define DINX 768
#define DINY 283
#define NHH 8
#define HKK 10
#define DKV 80
#define NORMF 0.31622776601683794f  // 1/sqrt(10)

#define NPLANE (BB * NXX * DKV)     // 1,310,720 floats per projected matrix
#define SLD 1032                    // S row stride (bf16 elems): 1024 + 8

// ws float layout:
//   Pq[4][NPLANE]  partials for Q      (head-major: ((b*8+h)*1024+n)*10+d)
//   Pk[2][NPLANE]  partials for K      (dim-major:  ((b*8+h)*10+d)*1024+n)
//   Pv[2][NPLANE]  partials for V      (dim-major)
//   Qhm[NPLANE], Kdm[NPLANE], Vdm[NPLANE]  reduced finals
// total 11*NPLANE*4B = 57.7 MB

// ---------------- Q projection: 1024 blocks (256 rowtiles x 4 ksplits), 256 thr ----------------
// wave w -> cols 20w..20w+19 (readfirstlane => W addr wave-uniform => s_load);
// lane = row within 64-row tile; X staged in LDS (coalesced, 33-pad conflict-free).
__global__ __launch_bounds__(256) void proj_q(
    const float* __restrict__ X, const float* __restrict__ Wq, float* __restrict__ Pq) {
  __shared__ float Xs[64 * 33];
  const int t = threadIdx.x;
  const int rt = blockIdx.x >> 2;
  const int ks = blockIdx.x & 3;
  const int w = __builtin_amdgcn_readfirstlane(t >> 6);  // force SGPR
  const int lane = t & 63;
  const int cbase = w * 20;
  const int kbase = ks * 192;

  float acc[20];
#pragma unroll
  for (int c = 0; c < 20; ++c) acc[c] = 0.f;

#pragma unroll 1
  for (int ch = 0; ch < 6; ++ch) {
    const int dk = kbase + ch * 32;
    __syncthreads();
    for (int u = t; u < 2048; u += 256) {
      const int r = u >> 5, c = u & 31;
      Xs[r * 33 + c] = X[(size_t)(rt * 64 + r) * DINX + dk + c];
    }
    __syncthreads();
    float xv[32];
#pragma unroll
    for (int k = 0; k < 32; ++k) xv[k] = Xs[lane * 33 + k];
#pragma unroll
    for (int c = 0; c < 20; ++c) {
      const float* wr = Wq + (size_t)(cbase + c) * DINX + dk;  // wave-uniform -> s_load
#pragma unroll
      for (int k = 0; k < 32; ++k) acc[c] = fmaf(wr[k], xv[k], acc[c]);
    }
  }

  const int row = rt * 64 + lane;
  const int b = row >> 10, n = row & 1023;
  float* dst = Pq + (size_t)ks * NPLANE;
#pragma unroll
  for (int c = 0; c < 20; ++c) {
    const int cc = cbase + c, h = cc / 10, d = cc - 10 * h;
    dst[(((size_t)b * NHH + h) * 1024 + n) * 10 + d] = acc[c];
  }
}

// ---------------- K/V projection: 512 blocks (256 rowtiles x 2 ksplits), 512 thr ----------------
// waves 0-3 -> K cols 20w; waves 4-7 -> V cols 20(w-4). Shared Y tile in LDS.
// ksplit 0: dims [0,160) (5 chunks); ksplit 1: [160,283) (3 full + 27-tail, W reads guarded).
__global__ __launch_bounds__(512) void proj_kv(
    const float* __restrict__ Y, const float* __restrict__ WK, const float* __restrict__ WV,
    float* __restrict__ Pk, float* __restrict__ Pv) {
  __shared__ float Xs[64 * 33];
  const int t = threadIdx.x;
  const int rt = blockIdx.x >> 1;
  const int ks = blockIdx.x & 1;
  const int w = __builtin_amdgcn_readfirstlane(t >> 6);
  const int lane = t & 63;
  const bool isV = (w >= 4);
  const int cbase = (isV ? (w - 4) : w) * 20;
  const float* W = isV ? WV : WK;
  const int kbase = ks * 160;
  const int nch = ks ? 4 : 5;

  float acc[20];
#pragma unroll
  for (int c = 0; c < 20; ++c) acc[c] = 0.f;

#pragma unroll 1
  for (int ch = 0; ch < nch; ++ch) {
    const int dk = kbase + ch * 32;
    __syncthreads();
    for (int u = t; u < 2048; u += 512) {
      const int r = u >> 5, c = u & 31;
      const int d = dk + c;
      Xs[r * 33 + c] = (d < DINY) ? Y[(size_t)(rt * 64 + r) * DINY + d] : 0.f;
    }
    __syncthreads();
    float xv[32];
#pragma unroll
    for (int k = 0; k < 32; ++k) xv[k] = Xs[lane * 33 + k];
    if (dk + 32 <= DINY) {
#pragma unroll
      for (int c = 0; c < 20; ++c) {
        const float* wr = W + (size_t)(cbase + c) * DINY + dk;
#pragma unroll
        for (int k = 0; k < 32; ++k) acc[c] = fmaf(wr[k], xv[k], acc[c]);
      }
    } else {  // dk == 256: only 27 valid dims (avoid OOB/NaN W reads)
#pragma unroll
      for (int c = 0; c < 20; ++c) {
        const float* wr = W + (size_t)(cbase + c) * DINY + dk;
#pragma unroll
        for (int k = 0; k < 27; ++k) acc[c] = fmaf(wr[k], xv[k], acc[c]);
      }
    }
  }

  const int row = rt * 64 + lane;
  const int b = row >> 10, n = row & 1023;
  float* dst = (isV ? Pv : Pk) + (size_t)ks * NPLANE;
#pragma unroll
  for (int c = 0; c < 20; ++c) {  // dim-major: per-c stores are lane-consecutive (coalesced)
    const int cc = cbase + c, h = cc / 10, d = cc - 10 * h;
    dst[(((size_t)b * NHH + h) * 10 + d) * 1024 + n] = acc[c];
  }
}

// ---------------- reduce partials -> finals (Qhm, Kdm, Vdm) ----------------
__global__ __launch_bounds__(256) void reduce_k(const float* __restrict__ ws, float* __restrict__ F) {
  const int NI = NPLANE / 4;  // f4 items per plane
  const float4* Pq = (const float4*)ws;
  const float4* Pk = (const float4*)(ws + (size_t)4 * NPLANE);
  const float4* Pv = (const float4*)(ws + (size_t)6 * NPLANE);
  float4* Fo = (float4*)F;
  for (int i = blockIdx.x * 256 + threadIdx.x; i < 3 * NI; i += gridDim.x * 256) {
    float4 s;
    if (i < NI) {
      float4 a = Pq[i], b2 = Pq[i + NI], c = Pq[i + 2 * NI], d = Pq[i + 3 * NI];
      s.x = a.x + b2.x + c.x + d.x; s.y = a.y + b2.y + c.y + d.y;
      s.z = a.z + b2.z + c.z + d.z; s.w = a.w + b2.w + c.w + d.w;
    } else if (i < 2 * NI) {
      const int j = i - NI;
      float4 a = Pk[j], b2 = Pk[j + NI];
      s.x = a.x + b2.x; s.y = a.y + b2.y; s.z = a.z + b2.z; s.w = a.w + b2.w;
    } else {
      const int j = i - 2 * NI;
      float4 a = Pv[j], b2 = Pv[j + NI];
      s.x = a.x + b2.x; s.y = a.y + b2.y; s.z = a.z + b2.z; s.w = a.w + b2.w;
    }
    Fo[i] = s;
  }
}

// ---------------- fused attention, zero-barrier k-loop ----------------
// block = (b,h, 32 q rows); 512 thr = 8 waves; wave owns 4 q rows x 64-lane k-split.
// K/V read DIRECTLY from global dim-major: kp[d*1024+k] is lane-consecutive b32 (coalesced,
// L1/L2-resident: 80 KB per (b,h)). No K/V LDS, no k-loop barriers. One barrier before phase B.
__global__ __launch_bounds__(512, 2) void attn_kernel(
    const float* __restrict__ Qhm, const float* __restrict__ Kdm,
    const float* __restrict__ Vdm, float* __restrict__ out_att,
    float* __restrict__ out_dist) {
  __shared__ __hip_bfloat16 S[32 * SLD];  // 66 KB
  __shared__ float rls[32];

  const int t = threadIdx.x;
  const int bid = blockIdx.x;
  const int qt = bid & 31;
  const int h = (bid >> 5) & 7;
  const int b = bid >> 8;

  const int w = __builtin_amdgcn_readfirstlane(t >> 6);
  const int kl = t & 63;

  float qr[4][10];
#pragma unroll
  for (int qi = 0; qi < 4; ++qi) {
    const float2* qp = (const float2*)(Qhm + (((size_t)b * NHH + h) * 1024 + qt * 32 + w * 4 + qi) * 10);
#pragma unroll
    for (int dd = 0; dd < 5; ++dd) {
      float2 v = qp[dd];
      qr[qi][2 * dd] = v.x * NORMF;
      qr[qi][2 * dd + 1] = v.y * NORMF;
    }
  }

  const float* kp = Kdm + (size_t)(b * NHH + h) * 10 * 1024;
  const float* vp = Vdm + (size_t)(b * NHH + h) * 10 * 1024;

  float acc[4][10];
#pragma unroll
  for (int qi = 0; qi < 4; ++qi)
#pragma unroll
    for (int d = 0; d < 10; ++d) acc[qi][d] = 0.f;
  float lsum[4] = {0.f, 0.f, 0.f, 0.f};

#pragma unroll 2
  for (int j = 0; j < 16; ++j) {
    const int k = j * 64 + kl;
    float kf[10];
#pragma unroll
    for (int d = 0; d < 10; ++d) kf[d] = kp[d * 1024 + k];
    float p[4];
#pragma unroll
    for (int qi = 0; qi < 4; ++qi) {
      float s = qr[qi][0] * kf[0] + qr[qi][1] * kf[1] + qr[qi][2] * kf[2] +
                qr[qi][3] * kf[3] + qr[qi][4] * kf[4] + qr[qi][5] * kf[5] +
                qr[qi][6] * kf[6] + qr[qi][7] * kf[7] + qr[qi][8] * kf[8] +
                qr[qi][9] * kf[9];
      p[qi] = __expf(s);
      lsum[qi] += p[qi];
      S[(w * 4 + qi) * SLD + k] = __float2bfloat16(p[qi]);
    }
    float vf[10];
#pragma unroll
    for (int d = 0; d < 10; ++d) vf[d] = vp[d * 1024 + k];
#pragma unroll
    for (int qi = 0; qi < 4; ++qi)
#pragma unroll
      for (int d = 0; d < 10; ++d) acc[qi][d] += p[qi] * vf[d];
  }

  // in-wave butterfly allreduce over the 64-lane k-split
#pragma unroll
  for (int off = 32; off; off >>= 1) {
#pragma unroll
    for (int qi = 0; qi < 4; ++qi) {
      lsum[qi] += __shfl_xor(lsum[qi], off);
#pragma unroll
      for (int d = 0; d < 10; ++d) acc[qi][d] += __shfl_xor(acc[qi][d], off);
    }
  }

  if (kl == 0) {
#pragma unroll
    for (int qi = 0; qi < 4; ++qi) {
      const int q = w * 4 + qi;
      const float rl = 1.0f / lsum[qi];
      rls[q] = rl;
      float* ap = out_att + ((size_t)b * NXX + qt * 32 + q) * DKV + h * HKK;
#pragma unroll
      for (int dd = 0; dd < 5; ++dd)
        *(float2*)&ap[2 * dd] = make_float2(acc[qi][2 * dd] * rl, acc[qi][2 * dd + 1] * rl);
    }
  }
  __syncthreads();

  // phase B: 32x1024, coalesced float4 stores
  const size_t dbase = (((size_t)(b * NHH + h)) * NXX + qt * 32) * NYY;
#pragma unroll 2
  for (int it = 0; it < 16; ++it) {
    const int e = it * 2048 + (t << 2);
    const int qq = e >> 10;
    const int kk = e & 1023;
    uint2 wv = *(const uint2*)&S[qq * SLD + kk];
    const float rlq = rls[qq];
    float4 o;
    o.x = __uint_as_float(wv.x << 16) * rlq;
    o.y = __uint_as_float(wv.x & 0xffff0000u) * rlq;
    o.z = __uint_as_float(wv.y << 16) * rlq;
    o.w = __uint_as_float(wv.y & 0xffff0000u) * rlq;
    *(float4*)(out_dist + dbase + (size_t)qq * NYY + kk) = o;
  }
}

extern "C" void kernel_launch(void* const* d_in, const int* in_sizes, int n_in,
                              void* d_out, int out_size, void* d_ws, size_t ws_size,
                              hipStream_t stream) {
  (void)in_sizes; (void)n_in; (void)out_size; (void)ws_size;
  const float* x = (const float*)d_in[0];
  const float* y = (const float*)d_in[1];
  // d_in[2] = attn_mask (dead arg in the reference forward)
  const float* Wq = (const float*)d_in[3];
  const float* Wk = (const float*)d_in[4];
  const float* Wv = (const float*)d_in[5];

  float* out = (float*)d_out;
  float* att_out = out;
  float* dist_out = out + (size_t)BB * NXX * DKV;

  float* ws = (float*)d_ws;
  float* Pq = ws;                                  // 4 planes
  float* Pk = ws + (size_t)4 * NPLANE;             // 2 planes
  float* Pv = ws + (size_t)6 * NPLANE;             // 2 planes
  float* F  = ws + (size_t)8 * NPLANE;             // Qhm, Kdm, Vdm
  float* Qhm = F;
  float* Kdm = F + (size_t)NPLANE;
  float* Vdm = F + (size_t)2 * NPLANE;

  proj_q<<<1024, 256, 0, stream>>>(x, Wq, Pq);
  proj_kv<<<512, 512, 0, stream>>>(y, Wk, Wv, Pk, Pv);
  reduce_k<<<2048, 256, 0, stream>>>(ws, F);
  attn_kernel<<<BB * NHH * 32, 512, 0, stream>>>(Qhm, Kdm, Vdm, att_out, dist_out);
}

// Round 6
// 483.946 us; speedup vs baseline: 3.2531x; 1.1651x over previous
//
#include <hip/hip_runtime.h>
#include <hip/hip_bf16.h>

#define BB 16
#define NXX 1024
#define NYY 1024
#define DINX 768
#define DINY 283
#define NHH 8
#define HKK 10
#define DKV 80
#define NORMF 0.31622776601683794f  // 1/sqrt(10)

#define NPLANE (BB * NXX * DKV)     // 1,310,720 floats per projected matrix
#define QT 16                       // q rows per attention block
#define SLD 1032                    // S row stride (bf16 elems): 1024 + 8

// ws float layout:
//   Pq[4][NPLANE]  partials for Q    (head-major: ((b*8+h)*1024+n)*10+d)
//   Pk[2][NPLANE]  partials for K    (dim-pair-major: (((b*8+h)*5+dp)*1024+n)*2+(d&1); K pre-scaled by NORMF)
//   Pv[2][NPLANE]  partials for V    (dim-pair-major)
//   Qhm[NPLANE], Kdm[NPLANE], Vdm[NPLANE]  reduced finals
// total 11*NPLANE*4B = 57.7 MB

// ---------------- Q projection: 1024 blocks (256 rowtiles x 4 ksplits), 256 thr ----------------
__global__ __launch_bounds__(256) void proj_q(
    const float* __restrict__ X, const float* __restrict__ Wq, float* __restrict__ Pq) {
  __shared__ float Xs[64 * 33];
  const int t = threadIdx.x;
  const int rt = blockIdx.x >> 2;
  const int ks = blockIdx.x & 3;
  const int w = __builtin_amdgcn_readfirstlane(t >> 6);  // force SGPR
  const int lane = t & 63;
  const int cbase = w * 20;
  const int kbase = ks * 192;

  float acc[20];
#pragma unroll
  for (int c = 0; c < 20; ++c) acc[c] = 0.f;

#pragma unroll 1
  for (int ch = 0; ch < 6; ++ch) {
    const int dk = kbase + ch * 32;
    __syncthreads();
    for (int u = t; u < 2048; u += 256) {
      const int r = u >> 5, c = u & 31;
      Xs[r * 33 + c] = X[(size_t)(rt * 64 + r) * DINX + dk + c];
    }
    __syncthreads();
    float xv[32];
#pragma unroll
    for (int k = 0; k < 32; ++k) xv[k] = Xs[lane * 33 + k];
#pragma unroll
    for (int c = 0; c < 20; ++c) {
      const float* wr = Wq + (size_t)(cbase + c) * DINX + dk;  // wave-uniform -> s_load
#pragma unroll
      for (int k = 0; k < 32; ++k) acc[c] = fmaf(wr[k], xv[k], acc[c]);
    }
  }

  const int row = rt * 64 + lane;
  const int b = row >> 10, n = row & 1023;
  float* dst = Pq + (size_t)ks * NPLANE;
#pragma unroll
  for (int c = 0; c < 20; ++c) {
    const int cc = cbase + c, h = cc / 10, d = cc - 10 * h;
    dst[(((size_t)b * NHH + h) * 1024 + n) * 10 + d] = acc[c];
  }
}

// ---------------- K/V projection: 512 blocks (256 rowtiles x 2 ksplits), 512 thr ----------------
// waves 0-3 -> K cols 20w; waves 4-7 -> V cols 20(w-4). Shared Y tile in LDS.
// K output pre-scaled by NORMF; both K,V stored dim-pair-major for b64 attention loads.
__global__ __launch_bounds__(512) void proj_kv(
    const float* __restrict__ Y, const float* __restrict__ WK, const float* __restrict__ WV,
    float* __restrict__ Pk, float* __restrict__ Pv) {
  __shared__ float Xs[64 * 33];
  const int t = threadIdx.x;
  const int rt = blockIdx.x >> 1;
  const int ks = blockIdx.x & 1;
  const int w = __builtin_amdgcn_readfirstlane(t >> 6);
  const int lane = t & 63;
  const bool isV = (w >= 4);
  const int cbase = (isV ? (w - 4) : w) * 20;
  const float* W = isV ? WV : WK;
  const int kbase = ks * 160;
  const int nch = ks ? 4 : 5;

  float acc[20];
#pragma unroll
  for (int c = 0; c < 20; ++c) acc[c] = 0.f;

#pragma unroll 1
  for (int ch = 0; ch < nch; ++ch) {
    const int dk = kbase + ch * 32;
    __syncthreads();
    for (int u = t; u < 2048; u += 512) {
      const int r = u >> 5, c = u & 31;
      const int d = dk + c;
      Xs[r * 33 + c] = (d < DINY) ? Y[(size_t)(rt * 64 + r) * DINY + d] : 0.f;
    }
    __syncthreads();
    float xv[32];
#pragma unroll
    for (int k = 0; k < 32; ++k) xv[k] = Xs[lane * 33 + k];
    if (dk + 32 <= DINY) {
#pragma unroll
      for (int c = 0; c < 20; ++c) {
        const float* wr = W + (size_t)(cbase + c) * DINY + dk;
#pragma unroll
        for (int k = 0; k < 32; ++k) acc[c] = fmaf(wr[k], xv[k], acc[c]);
      }
    } else {  // dk == 256: only 27 valid dims
#pragma unroll
      for (int c = 0; c < 20; ++c) {
        const float* wr = W + (size_t)(cbase + c) * DINY + dk;
#pragma unroll
        for (int k = 0; k < 27; ++k) acc[c] = fmaf(wr[k], xv[k], acc[c]);
      }
    }
  }

  const int row = rt * 64 + lane;
  const int b = row >> 10, n = row & 1023;
  float* dst = (isV ? Pv : Pk) + (size_t)ks * NPLANE;
  const float scale = isV ? 1.0f : NORMF;
#pragma unroll
  for (int c = 0; c < 20; ++c) {
    const int cc = cbase + c, h = cc / 10, d = cc - 10 * h, dp = d >> 1;
    dst[(((size_t)b * NHH + h) * 5 + dp) * 2048 + n * 2 + (d & 1)] = acc[c] * scale;
  }
}

// ---------------- reduce partials -> finals (Qhm, Kdm, Vdm) ----------------
__global__ __launch_bounds__(256) void reduce_k(const float* __restrict__ ws, float* __restrict__ F) {
  const int NI = NPLANE / 4;  // f4 items per plane
  const float4* Pq = (const float4*)ws;
  const float4* Pk = (const float4*)(ws + (size_t)4 * NPLANE);
  const float4* Pv = (const float4*)(ws + (size_t)6 * NPLANE);
  float4* Fo = (float4*)F;
  for (int i = blockIdx.x * 256 + threadIdx.x; i < 3 * NI; i += gridDim.x * 256) {
    float4 s;
    if (i < NI) {
      float4 a = Pq[i], b2 = Pq[i + NI], c = Pq[i + 2 * NI], d = Pq[i + 3 * NI];
      s.x = a.x + b2.x + c.x + d.x; s.y = a.y + b2.y + c.y + d.y;
      s.z = a.z + b2.z + c.z + d.z; s.w = a.w + b2.w + c.w + d.w;
    } else if (i < 2 * NI) {
      const int j = i - NI;
      float4 a = Pk[j], b2 = Pk[j + NI];
      s.x = a.x + b2.x; s.y = a.y + b2.y; s.z = a.z + b2.z; s.w = a.w + b2.w;
    } else {
      const int j = i - 2 * NI;
      float4 a = Pv[j], b2 = Pv[j + NI];
      s.x = a.x + b2.x; s.y = a.y + b2.y; s.z = a.z + b2.z; s.w = a.w + b2.w;
    }
    Fo[i] = s;
  }
}

// ---------------- fused attention ----------------
// block = (b,h, 16 q rows); 256 thr = 4 waves; wave owns 4 q rows x 64-lane k-split.
// S tile 33 KB -> 4 blocks/CU (~16 waves/CU resident, 4x r5).
// K/V read direct from global dim-pair-major (b64 coalesced, L2-resident). Q rows are
// wave-uniform -> scalar loads. One barrier between phases.
__global__ __launch_bounds__(256, 4) void attn_kernel(
    const float* __restrict__ Qhm, const float* __restrict__ Kdm,
    const float* __restrict__ Vdm, float* __restrict__ out_att,
    float* __restrict__ out_dist) {
  __shared__ __hip_bfloat16 S[QT * SLD];  // 33024 B
  __shared__ float rls[QT];

  const int t = threadIdx.x;
  const int bid = blockIdx.x;
  const int qt = bid & 63;          // q-tile fast -> same (b,h) adjacent for K/V L2 reuse
  const int h = (bid >> 6) & 7;
  const int b = bid >> 9;
  const int bh = b * NHH + h;

  const int w = __builtin_amdgcn_readfirstlane(t >> 6);
  const int kl = t & 63;

  // q rows for this wave (wave-uniform addresses -> scalar loads; K carries the NORM scale)
  float qr[4][10];
#pragma unroll
  for (int qi = 0; qi < 4; ++qi) {
    const float* qp = Qhm + ((size_t)bh * 1024 + qt * QT + w * 4 + qi) * 10;
#pragma unroll
    for (int d = 0; d < 10; ++d) qr[qi][d] = qp[d];
  }

  const float2* kp2 = (const float2*)Kdm + (size_t)bh * 5 * 1024;
  const float2* vp2 = (const float2*)Vdm + (size_t)bh * 5 * 1024;

  float acc[4][10];
#pragma unroll
  for (int qi = 0; qi < 4; ++qi)
#pragma unroll
    for (int d = 0; d < 10; ++d) acc[qi][d] = 0.f;
  float lsum[4] = {0.f, 0.f, 0.f, 0.f};

#pragma unroll 2
  for (int j = 0; j < 16; ++j) {
    const int k = j * 64 + kl;
    float kf[10];
#pragma unroll
    for (int dp = 0; dp < 5; ++dp) {
      float2 v = kp2[dp * 1024 + k];
      kf[2 * dp] = v.x; kf[2 * dp + 1] = v.y;
    }
    float p[4];
#pragma unroll
    for (int qi = 0; qi < 4; ++qi) {
      float s = qr[qi][0] * kf[0] + qr[qi][1] * kf[1] + qr[qi][2] * kf[2] +
                qr[qi][3] * kf[3] + qr[qi][4] * kf[4] + qr[qi][5] * kf[5] +
                qr[qi][6] * kf[6] + qr[qi][7] * kf[7] + qr[qi][8] * kf[8] +
                qr[qi][9] * kf[9];
      p[qi] = __expf(s);
      lsum[qi] += p[qi];
      S[(w * 4 + qi) * SLD + k] = __float2bfloat16(p[qi]);
    }
    float vf[10];
#pragma unroll
    for (int dp = 0; dp < 5; ++dp) {
      float2 v = vp2[dp * 1024 + k];
      vf[2 * dp] = v.x; vf[2 * dp + 1] = v.y;
    }
#pragma unroll
    for (int qi = 0; qi < 4; ++qi)
#pragma unroll
      for (int d = 0; d < 10; ++d) acc[qi][d] += p[qi] * vf[d];
  }

  // in-wave butterfly allreduce over the 64-lane k-split
#pragma unroll
  for (int off = 32; off; off >>= 1) {
#pragma unroll
    for (int qi = 0; qi < 4; ++qi) {
      lsum[qi] += __shfl_xor(lsum[qi], off);
#pragma unroll
      for (int d = 0; d < 10; ++d) acc[qi][d] += __shfl_xor(acc[qi][d], off);
    }
  }

  if (kl == 0) {
#pragma unroll
    for (int qi = 0; qi < 4; ++qi) {
      const int q = w * 4 + qi;
      const float rl = 1.0f / lsum[qi];
      rls[q] = rl;
      float* ap = out_att + ((size_t)b * NXX + qt * QT + q) * DKV + h * HKK;
#pragma unroll
      for (int dd = 0; dd < 5; ++dd)
        *(float2*)&ap[2 * dd] = make_float2(acc[qi][2 * dd] * rl, acc[qi][2 * dd + 1] * rl);
    }
  }
  __syncthreads();

  // phase B: 16x1024, coalesced float4 stores
  const size_t dbase = ((size_t)bh * NXX + qt * QT) * NYY;
#pragma unroll 2
  for (int it = 0; it < 16; ++it) {
    const int e = it * 1024 + (t << 2);
    const int qq = e >> 10;
    const int kk = e & 1023;
    uint2 wv = *(const uint2*)&S[qq * SLD + kk];
    const float rlq = rls[qq];
    float4 o;
    o.x = __uint_as_float(wv.x << 16) * rlq;
    o.y = __uint_as_float(wv.x & 0xffff0000u) * rlq;
    o.z = __uint_as_float(wv.y << 16) * rlq;
    o.w = __uint_as_float(wv.y & 0xffff0000u) * rlq;
    *(float4*)(out_dist + dbase + (size_t)qq * NYY + kk) = o;
  }
}

extern "C" void kernel_launch(void* const* d_in, const int* in_sizes, int n_in,
                              void* d_out, int out_size, void* d_ws, size_t ws_size,
                              hipStream_t stream) {
  (void)in_sizes; (void)n_in; (void)out_size; (void)ws_size;
  const float* x = (const float*)d_in[0];
  const float* y = (const float*)d_in[1];
  // d_in[2] = attn_mask (dead arg in the reference forward)
  const float* Wq = (const float*)d_in[3];
  const float* Wk = (const float*)d_in[4];
  const float* Wv = (const float*)d_in[5];

  float* out = (float*)d_out;
  float* att_out = out;
  float* dist_out = out + (size_t)BB * NXX * DKV;

  float* ws = (float*)d_ws;
  float* Pq = ws;                                  // 4 planes
  float* Pk = ws + (size_t)4 * NPLANE;             // 2 planes
  float* Pv = ws + (size_t)6 * NPLANE;             // 2 planes
  float* F  = ws + (size_t)8 * NPLANE;             // Qhm, Kdm, Vdm
  float* Qhm = F;
  float* Kdm = F + (size_t)NPLANE;
  float* Vdm = F + (size_t)2 * NPLANE;

  proj_q<<<1024, 256, 0, stream>>>(x, Wq, Pq);
  proj_kv<<<512, 512, 0, stream>>>(y, Wk, Wv, Pk, Pv);
  reduce_k<<<2048, 256, 0, stream>>>(ws, F);
  attn_kernel<<<BB * NHH * 64, 256, 0, stream>>>(Qhm, Kdm, Vdm, att_out, dist_out);
}